// Round 2
// baseline (247.603 us; speedup 1.0000x reference)
//
#include <hip/hip_runtime.h>
#include <hip/hip_bf16.h>

#define Bsz   512
#define Tlen  1024
#define Ktag  48
#define NREAL 45          // tags 0..44 are real; 45=START, 46=STOP, 47=PAD
#define HALF_T 512
#define STOPT 46
#define NEGV  -10000.0f

__device__ __forceinline__ float wave_max(float v) {
#pragma unroll
    for (int off = 32; off > 0; off >>= 1)
        v = fmaxf(v, __shfl_xor(v, off, 64));
    return v;
}

__device__ __forceinline__ float wave_sum(float v) {
#pragma unroll
    for (int off = 32; off > 0; off >>= 1)
        v += __shfl_xor(v, off, 64);
    return v;
}

// broadcast lane `l`'s value to all lanes (uniform l) via v_readlane
__device__ __forceinline__ float bcast(float v, int l) {
    return __int_as_float(__builtin_amdgcn_readlane(__float_as_int(v), l));
}

template <bool BF16>
__device__ __forceinline__ float ld(const void* p, size_t i) {
    if constexpr (BF16) {
        unsigned int u = ((const unsigned short*)p)[i];
        return __uint_as_float(u << 16);
    } else {
        return ((const float*)p)[i];
    }
}

// ws layout (floats): uF[B][K], MF[B], uB[B][K], MB[B]
template <bool BF16>
__device__ void crf_chains(const void* __restrict__ h, const void* __restrict__ mask,
                           const void* __restrict__ trans, float* __restrict__ ws) {
    __shared__ float ltr[Ktag][Ktag + 1];
    const int lane = threadIdx.x;
    const int bid  = blockIdx.x;
    const bool fwd = bid < Bsz;
    const int b    = fwd ? bid : bid - Bsz;

    for (int idx = lane; idx < Ktag * Ktag; idx += 64) {
        int i = idx / Ktag;
        ltr[i][idx - i * Ktag] = ld<BF16>(trans, (size_t)idx);
    }
    __syncthreads();

    // Per-lane row (fwd) / column (bwd) of E = exp(trans). Lanes >= K get zeros
    // so their state stays 0 and never pollutes reductions.
    float E[Ktag];
#pragma unroll
    for (int j = 0; j < Ktag; j++) E[j] = 0.f;
    if (lane < Ktag) {
        if (fwd) {
#pragma unroll
            for (int j = 0; j < Ktag; j++) E[j] = __expf(ltr[lane][j]);
        } else {
#pragma unroll
            for (int i = 0; i < Ktag; i++) E[i] = __expf(ltr[i][lane]);
        }
    }

    const int li = (lane < Ktag) ? lane : (Ktag - 1);  // clamped index for loads
    const size_t hb = (size_t)b * Tlen * Ktag;

    float* uF = ws;
    float* MF = ws + (size_t)Bsz * Ktag;
    float* uB = MF + Bsz;
    float* MB = uB + (size_t)Bsz * Ktag;

    float u = 0.f, M = 0.f;

    if (fwd) {
        // ---- exact step 0 in log space (exp-domain underflows here) ----
        // CRITICAL: the renorm scale must track the REAL tag block (lanes
        // 0..44). score[PAD] ~ O(1) vs real tags ~ -10000+c: including PAD
        // in the max underflows every real tag to 0 and the combine (whose
        // backward weight on PAD is exactly 0) becomes log(0) = -inf.
        // START/STOP/PAD are excluded here; E's zero columns for STOP/PAD
        // keep the real-tag recursion exact afterwards.
        {
            float e0 = ld<BF16>(h, hb + li);
            float mx = -3.0e38f;
#pragma unroll
            for (int j = 0; j < Ktag; j++) {
                float v = ltr[li][j] + (j == STOPT ? 0.f : NEGV);
                mx = fmaxf(mx, v);
            }
            float s = 0.f;
#pragma unroll
            for (int j = 0; j < Ktag; j++) {
                float v = ltr[li][j] + (j == STOPT ? 0.f : NEGV);
                s += __expf(v - mx);
            }
            float sc = e0 + mx + __logf(s);
            if (lane >= NREAL) sc = -3.0e38f;   // drop START/STOP/PAD from state+max
            float m1 = wave_max(sc);
            M = m1;
            u = (lane < NREAL) ? __expf(sc - m1) : 0.f;
        }
        // ---- t = 1 .. 511, exp-domain, groups of 4 with renorm ----
        float em[4], emn[4];
#pragma unroll
        for (int k = 0; k < 4; k++) {
            int tt = 1 + k; if (tt > HALF_T - 1) tt = HALF_T - 1;
            em[k] = ld<BF16>(h, hb + (size_t)tt * Ktag + li);
        }
        for (int t = 1; t < HALF_T; t += 4) {
#pragma unroll
            for (int k = 0; k < 4; k++) {  // prefetch next group
                int tt = t + 4 + k; if (tt > HALF_T - 1) tt = HALF_T - 1;
                emn[k] = ld<BF16>(h, hb + (size_t)tt * Ktag + li);
            }
#pragma unroll
            for (int k = 0; k < 4; k++) {
                if (t + k < HALF_T) {
                    float ee = __expf(em[k]);
                    float a0 = 0.f, a1 = 0.f, a2 = 0.f, a3 = 0.f;
#pragma unroll
                    for (int j = 0; j < Ktag; j += 4) {
                        a0 = fmaf(E[j + 0], bcast(u, j + 0), a0);
                        a1 = fmaf(E[j + 1], bcast(u, j + 1), a1);
                        a2 = fmaf(E[j + 2], bcast(u, j + 2), a2);
                        a3 = fmaf(E[j + 3], bcast(u, j + 3), a3);
                    }
                    u = ((a0 + a1) + (a2 + a3)) * ee;
                }
            }
            float m = wave_max(u);
            u *= 1.0f / m;
            M += __logf(m);
#pragma unroll
            for (int k = 0; k < 4; k++) em[k] = emn[k];
        }
        if (lane < Ktag) uF[(size_t)b * Ktag + lane] = u;
        if (lane == 0) MF[b] = M;
    } else {
        // ---- sequence length (mask is monotone: t < len) ----
        float c = 0.f;
        for (int t0 = lane; t0 < Tlen; t0 += 64)
            c += ld<BF16>(mask, (size_t)b * Tlen + t0);
        c = wave_sum(c);
        int len = (int)(c + 0.5f);

        // ---- init gamma = exp(trans[STOP, :]) (O(1) on real tags; exactly 0
        //      on STOP/PAD, which is what kills the PAD path in the combine) ----
        float g = (lane < Ktag) ? ltr[STOPT][lane] : -3.0e38f;
        float m0 = wave_max(g);
        M = m0;
        u = (lane < Ktag) ? __expf(g - m0) : 0.f;

        // ---- t = len-1 down to 512 ----
        int t0 = len - 1;
        float em[4], emn[4];
#pragma unroll
        for (int k = 0; k < 4; k++) {
            int tt = t0 - k; if (tt < HALF_T) tt = HALF_T;
            em[k] = ld<BF16>(h, hb + (size_t)tt * Ktag + li);
        }
        for (int tg = t0; tg >= HALF_T; tg -= 4) {
#pragma unroll
            for (int k = 0; k < 4; k++) {  // prefetch next group
                int tt = tg - 4 - k; if (tt < HALF_T) tt = HALF_T;
                emn[k] = ld<BF16>(h, hb + (size_t)tt * Ktag + li);
            }
#pragma unroll
            for (int k = 0; k < 4; k++) {
                if (tg - k >= HALF_T) {
                    float ee = __expf(em[k]);
                    float v = u * ee;  // gamma' = E^T (exp(emit) .* gamma)
                    float a0 = 0.f, a1 = 0.f, a2 = 0.f, a3 = 0.f;
#pragma unroll
                    for (int j = 0; j < Ktag; j += 4) {
                        a0 = fmaf(E[j + 0], bcast(v, j + 0), a0);
                        a1 = fmaf(E[j + 1], bcast(v, j + 1), a1);
                        a2 = fmaf(E[j + 2], bcast(v, j + 2), a2);
                        a3 = fmaf(E[j + 3], bcast(v, j + 3), a3);
                    }
                    u = (a0 + a1) + (a2 + a3);
                }
            }
            float m = wave_max(u);
            u *= 1.0f / m;
            M += __logf(m);
#pragma unroll
            for (int k = 0; k < 4; k++) em[k] = emn[k];
        }
        if (lane < Ktag) uB[(size_t)b * Ktag + lane] = u;
        if (lane == 0) MB[b] = M;
    }
}

__global__ void __launch_bounds__(64) crf_main(const void* __restrict__ h,
                                               const void* __restrict__ mask,
                                               const void* __restrict__ trans,
                                               float* __restrict__ ws) {
    // dtype sniff: mask[b=0,t=0] == 1.0 always (len >= 512). bf16 -> first
    // uint16 is 0x3F80; f32 -> first uint16 is the low mantissa half, 0x0000.
    bool isbf16 = (((const unsigned short*)mask)[0] == 0x3F80);
    if (isbf16) crf_chains<true>(h, mask, trans, ws);
    else        crf_chains<false>(h, mask, trans, ws);
}

__global__ void __launch_bounds__(64) crf_combine(const void* __restrict__ mask,
                                                  const float* __restrict__ ws,
                                                  void* __restrict__ out) {
    const int b = blockIdx.x;
    const int lane = threadIdx.x;
    const float* uF = ws;
    const float* MF = ws + (size_t)Bsz * Ktag;
    const float* uB = MF + Bsz;
    const float* MB = uB + (size_t)Bsz * Ktag;

    float p = (lane < Ktag) ? uF[(size_t)b * Ktag + lane] * uB[(size_t)b * Ktag + lane] : 0.f;
    float s = wave_sum(p);
    float ans = MF[b] + MB[b] + __logf(s);

    bool isbf16 = (((const unsigned short*)mask)[0] == 0x3F80);
    if (lane == 0) {
        if (isbf16) {
            unsigned int x = __float_as_uint(ans);
            unsigned int r = (x + 0x7FFFu + ((x >> 16) & 1u)) >> 16;  // RNE to bf16
            ((unsigned short*)out)[b] = (unsigned short)r;
        } else {
            ((float*)out)[b] = ans;
        }
    }
}

extern "C" void kernel_launch(void* const* d_in, const int* in_sizes, int n_in,
                              void* d_out, int out_size, void* d_ws, size_t ws_size,
                              hipStream_t stream) {
    const void* h     = d_in[0];  // (B,T,K)
    const void* mask  = d_in[1];  // (B,T)
    const void* trans = d_in[2];  // (K,K)
    float* ws = (float*)d_ws;     // needs 2*(B*K + B) floats = ~200 KB

    hipLaunchKernelGGL(crf_main, dim3(2 * Bsz), dim3(64), 0, stream, h, mask, trans, ws);
    hipLaunchKernelGGL(crf_combine, dim3(Bsz), dim3(64), 0, stream, mask, ws, d_out);
}